// Round 2
// baseline (270.354 us; speedup 1.0000x reference)
//
#include <hip/hip_runtime.h>
#include <hip/hip_bf16.h>
#include <math.h>

// Problem constants (from reference):
//   x: [B=16, C=425, H=76, W=76] f32, C = NUM(5) * LPA(85)
//   out: [16, 5*83=415, 76, 76] f32
//   per anchor: out[0]=sig(in[0]), out[1]=sig(in[1]), out[2]=sig(in[4]),
//               out[3+c]=softmax(in[5..84])[c]   (in[2],in[3] dropped)
#define BATCH 16
#define NUMA 5
#define LPA 85
#define OUTC 83
#define HW (76 * 76)        // 5776
#define CLS 80

__device__ __forceinline__ float fast_sigmoid(float v) {
    // 1 / (1 + exp(-v)); exp via exp2 (v_exp_f32)
    float e = __expf(-v);
    return __frcp_rn(1.0f + e);
}

__global__ __launch_bounds__(256) void region_kernel(
        const float* __restrict__ x, float* __restrict__ out) {
    // One thread per (b, n, h, w). Total = BATCH*NUMA*HW = 462080 = 1805*256.
    const int idx = blockIdx.x * blockDim.x + threadIdx.x;
    const int total = BATCH * NUMA * HW;
    if (idx >= total) return;

    const int hw = idx % HW;
    const int bn = idx / HW;   // b*NUMA + n

    const float* __restrict__ px = x + (size_t)bn * LPA * HW + hw;
    float* __restrict__ po = out + (size_t)bn * OUTC * HW + hw;

    // Load the 3 sigmoid channels
    const float v_x = px[0 * HW];
    const float v_y = px[1 * HW];
    const float v_o = px[4 * HW];

    // Load 80 class logits into registers (fully unrolled -> stays in VGPRs)
    float cls[CLS];
    #pragma unroll
    for (int c = 0; c < CLS; ++c) {
        cls[c] = px[(5 + c) * HW];
    }

    // Max reduce
    float m = cls[0];
    #pragma unroll
    for (int c = 1; c < CLS; ++c) m = fmaxf(m, cls[c]);

    // exp + sum
    float sum = 0.0f;
    #pragma unroll
    for (int c = 0; c < CLS; ++c) {
        float e = __expf(cls[c] - m);
        cls[c] = e;
        sum += e;
    }
    const float inv = __frcp_rn(sum);

    // Writes: xy, obj, then normalized class probs
    po[0 * HW] = fast_sigmoid(v_x);
    po[1 * HW] = fast_sigmoid(v_y);
    po[2 * HW] = fast_sigmoid(v_o);
    #pragma unroll
    for (int c = 0; c < CLS; ++c) {
        po[(3 + c) * HW] = cls[c] * inv;
    }
}

extern "C" void kernel_launch(void* const* d_in, const int* in_sizes, int n_in,
                              void* d_out, int out_size, void* d_ws, size_t ws_size,
                              hipStream_t stream) {
    const float* x = (const float*)d_in[0];
    float* out = (float*)d_out;

    const int total = BATCH * NUMA * HW;   // 462080
    const int block = 256;
    const int grid = (total + block - 1) / block;  // 1805, exact

    region_kernel<<<grid, block, 0, stream>>>(x, out);
}